// Round 9
// baseline (89.806 us; speedup 1.0000x reference)
//
#include <hip/hip_runtime.h>

// Depth-4 path signature, B=128, L=128, C=12, fp32. Round 9.
// Single fused kernel. Key change: the 12-wide d_l broadcast (operand of the
// level-4 acc FMAs) moves OFF the per-CU LDS pipe onto the 4x-wider VALU
// pipe via v_readlane: one ds_read_b128 per 4 steps puts channel-c's 4
// increments in lane c; 12 readlane/step (compile-time lane index) yield
// SGPR operands for v_fmac. Per-thread d_i/d_j/d_k still come from the
// padded transposed LDS table (<=2-way conflicts = free).
// Grid 512 = (batch, j-half x k-half); 448 thr (432 act = 12i x 6j x 6k);
// 2 blocks/CU = 14 waves/CU. No barriers in the 32-iter main loop.

#define NC    12
#define NPTS  128
#define OUT_PER_B 22620      // 12 + 144 + 1728 + 20736
#define BLOCK 448
#define PADQ  33             // float4 row stride in LDS (132 floats)

__device__ __forceinline__ float rl(float v, int lane) {
    return __int_as_float(__builtin_amdgcn_readlane(__float_as_int(v), lane));
}

__global__ __launch_bounds__(BLOCK, 4)
void sig_kernel(const float* __restrict__ path, float* __restrict__ out) {
    const int bid = blockIdx.x;
    const int b  = bid >> 2;          // batch
    const int q  = bid & 3;           // quarter = (j-half, k-half)
    const int jq = q >> 1;
    const int kq = q & 1;
    const int t  = threadIdx.x;

    __shared__ __align__(16) float4 DT4[NC * PADQ];     // 6336 B transposed incs
    __shared__ __align__(16) float4 P4[NPTS * NC / 4];  // 6144 B path staging

    // ---- stage path (coalesced float4), build transposed increment table ----
    const float4* pb4 = (const float4*)(path + (size_t)b * (NPTS * NC));
    if (t < 384) P4[t] = pb4[t];
    __syncthreads();
    if (t < 384) {
        const int c  = t >> 5;        // 0..11
        const int sq = t & 31;        // 0..31
        const float* P = (const float*)P4;
        float d[4];
        #pragma unroll
        for (int e = 0; e < 4; ++e) {
            int s = 4 * sq + e;
            d[e] = (s < NPTS - 1) ? (P[(s + 1) * NC + c] - P[s * NC + c]) : 0.f;
        }
        DT4[c * PADQ + sq] = make_float4(d[0], d[1], d[2], d[3]);
    }
    __syncthreads();

    // ---- index map (pad threads duplicate work; stores guarded later) ----
    const int ta  = (t < 432) ? t : (t - 432);
    const int i   = ta / 36;           // 0..11
    const int r   = ta - i * 36;
    const int jl  = r / 6;             // 0..5
    const int kl  = r - jl * 6;        // 0..5
    const int j   = jq * 6 + jl;       // 0..11
    const int k   = kq * 6 + kl;       // 0..11

    float acc[12];
    #pragma unroll
    for (int l = 0; l < 12; ++l) acc[l] = 0.f;
    float s3 = 0.f, s2 = 0.f, s1 = 0.f;

    const int lane = t & 63;
    const float4* dti = &DT4[i * PADQ];
    const float4* dtj = &DT4[j * PADQ];
    const float4* dtk = &DT4[k * PADQ];
    const float4* dtv = &DT4[(lane < 12 ? lane : 11) * PADQ]; // lane c -> channel c

    for (int sq = 0; sq < 32; ++sq) {
        float4 di4 = dti[sq];
        float4 dj4 = dtj[sq];
        float4 dk4 = dtk[sq];
        float4 dv4 = dtv[sq];          // lane c holds d[4sq..4sq+3][c]

        #pragma unroll
        for (int u = 0; u < 4; ++u) {
            const float di = (&di4.x)[u];
            const float dj = (&dj4.x)[u];
            const float dk = (&dk4.x)[u];
            const float dv = (&dv4.x)[u];

            // Horner-factored Chen step (identical arithmetic to R2..R8)
            float A4 = (s1 + 0.25f * di) * (1.f / 3.f);
            float B4 = (s2 + dj * A4) * 0.5f;
            float C3 = s3 + dk * B4;

            // d_l via readlane -> SGPR operand of v_fmac
            #pragma unroll
            for (int l = 0; l < 12; ++l)
                acc[l] += C3 * rl(dv, l);

            float A3 = (s1 + di * (1.f / 3.f)) * 0.5f;
            float C2 = s2 + dj * A3;
            s3 += dk * C2;
            s2 += dj * (s1 + 0.5f * di);
            s1 += di;
        }
    }

    if (t < 432) {
        float* ob = out + (size_t)b * OUT_PER_B;
        if (q == 0 && jl == 0 && kl == 0) ob[i] = s1;      // level 1 (once)
        if (kl == 0) ob[12 + i * 12 + j] = s2;             // level 2
        const int ijk = (i * 12 + j) * 12 + k;
        ob[156 + ijk] = s3;                                // level 3
        float4* o4 = (float4*)(ob + 1884 + (size_t)ijk * 12);  // level 4, 48B
        o4[0] = make_float4(acc[0], acc[1], acc[2],  acc[3]);
        o4[1] = make_float4(acc[4], acc[5], acc[6],  acc[7]);
        o4[2] = make_float4(acc[8], acc[9], acc[10], acc[11]);
    }
}

extern "C" void kernel_launch(void* const* d_in, const int* in_sizes, int n_in,
                              void* d_out, int out_size, void* d_ws, size_t ws_size,
                              hipStream_t stream) {
    const float* path = (const float*)d_in[0];
    float* out = (float*)d_out;
    const int nbatch = in_sizes[0] / (NPTS * NC);   // = 128
    sig_kernel<<<nbatch * 4, BLOCK, 0, stream>>>(path, out);
}

// Round 10
// 82.944 us; speedup vs baseline: 1.0827x; 1.0827x over previous
//
#include <hip/hip_runtime.h>

// Depth-4 path signature, B=128, L=128, C=12, fp32. Round 10.
// Validated model: broadcasting the 48B/step l-row costs ~36cy/step per WAVE
// on the single per-CU LDS pipe (R2: 13.5w -> 30us), and neither SMEM
// (s_loads retire out-of-order -> only lgkmcnt(0) waits, R5/6/8) nor
// readlane (VALU->SGPR->VALU hazard, R9: 41us) escapes it. Lever: fewer
// ingesting waves. Thread owns a k-QUAD (4 chains, 48 acc FMAs/step) ->
// 3.375 active waves/CU instead of 13.5. Per-CU/step: LDS ~216cy (bound),
// VALU ~128cy (hidden). Grid 512 = (batch, i-triple), block 128 (108 active),
// 2 blocks/CU. Fused prep (increments built in LDS). No barriers in loop.

#define NC    12
#define NPTS  128
#define OUT_PER_B 22620      // 12 + 144 + 1728 + 20736
#define BLOCK 128
#define PADQ  33             // float4 row stride in transposed LDS table

__global__ __launch_bounds__(BLOCK, 2)
void sig_kernel(const float* __restrict__ path, float* __restrict__ out) {
    const int bid = blockIdx.x;
    const int b  = bid >> 2;          // batch
    const int iq = bid & 3;           // i-triple selector
    const int t  = threadIdx.x;

    __shared__ __align__(16) float4 P4[384];          // 6144 B staged path
    __shared__ __align__(16) float4 DT4[NC * PADQ];   // 6336 B transposed incs
    __shared__ __align__(16) float  Drow[NPTS * NC];  // 6144 B row-major incs

    // ---- stage path, build increment tables (both layouts) ----
    const float4* pb4 = (const float4*)(path + (size_t)b * (NPTS * NC));
    #pragma unroll
    for (int v = 0; v < 3; ++v) P4[t + 128 * v] = pb4[t + 128 * v];
    __syncthreads();
    {
        const float* P = (const float*)P4;
        #pragma unroll
        for (int v = 0; v < 3; ++v) {
            int idx = t + 128 * v;        // 0..383
            int c  = idx >> 5;            // 0..11
            int sq = idx & 31;            // 0..31
            float d[4];
            #pragma unroll
            for (int e = 0; e < 4; ++e) {
                int s = 4 * sq + e;
                d[e] = (s < NPTS - 1) ? (P[(s + 1) * NC + c] - P[s * NC + c]) : 0.f;
                Drow[s * NC + c] = d[e];
            }
            DT4[c * PADQ + sq] = make_float4(d[0], d[1], d[2], d[3]);
        }
    }
    __syncthreads();

    if (t < 108) {
        const int il = t / 36;            // 0..2
        const int r  = t - il * 36;
        const int j  = r / 3;             // 0..11
        const int kq = r - j * 3;         // 0..2
        const int i  = iq * 3 + il;       // 0..11
        const int k0 = kq * 4;            // 0,4,8

        float acc[4][12];
        #pragma unroll
        for (int q = 0; q < 4; ++q)
            #pragma unroll
            for (int l = 0; l < 12; ++l) acc[q][l] = 0.f;
        float s3[4] = {0.f, 0.f, 0.f, 0.f};
        float s2 = 0.f, s1 = 0.f;

        const float4* dti  = &DT4[i * PADQ];
        const float4* dtj  = &DT4[j * PADQ];
        const float4* dtk0 = &DT4[(k0 + 0) * PADQ];
        const float4* dtk1 = &DT4[(k0 + 1) * PADQ];
        const float4* dtk2 = &DT4[(k0 + 2) * PADQ];
        const float4* dtk3 = &DT4[(k0 + 3) * PADQ];

        for (int sq = 0; sq < 32; ++sq) {
            // per-thread transposed reads: 6 b128 per 4 steps (<=2-way = free)
            float4 di4 = dti[sq];
            float4 dj4 = dtj[sq];
            float4 dka = dtk0[sq];
            float4 dkb = dtk1[sq];
            float4 dkc = dtk2[sq];
            float4 dkd = dtk3[sq];
            const float4* dvp = (const float4*)&Drow[sq * 48];

            #pragma unroll
            for (int u = 0; u < 4; ++u) {
                // 12 block-uniform increments: 3 broadcast b128 per step
                float4 va = dvp[3 * u + 0];
                float4 vb = dvp[3 * u + 1];
                float4 vc = dvp[3 * u + 2];

                const float di = (&di4.x)[u];
                const float dj = (&dj4.x)[u];

                // Horner coefficients shared across the k-quad (same
                // arithmetic order per chain as R2..R9)
                float A4 = (s1 + 0.25f * di) * (1.f / 3.f);
                float B4 = (s2 + dj * A4) * 0.5f;
                float A3 = (s1 + di * (1.f / 3.f)) * 0.5f;
                float C2 = s2 + dj * A3;

                float dk[4] = {(&dka.x)[u], (&dkb.x)[u], (&dkc.x)[u], (&dkd.x)[u]};
                #pragma unroll
                for (int q = 0; q < 4; ++q) {
                    float C3 = s3[q] + dk[q] * B4;
                    acc[q][0]  += C3 * va.x;  acc[q][1]  += C3 * va.y;
                    acc[q][2]  += C3 * va.z;  acc[q][3]  += C3 * va.w;
                    acc[q][4]  += C3 * vb.x;  acc[q][5]  += C3 * vb.y;
                    acc[q][6]  += C3 * vb.z;  acc[q][7]  += C3 * vb.w;
                    acc[q][8]  += C3 * vc.x;  acc[q][9]  += C3 * vc.y;
                    acc[q][10] += C3 * vc.z;  acc[q][11] += C3 * vc.w;
                    s3[q] += dk[q] * C2;
                }
                s2 += dj * (s1 + 0.5f * di);
                s1 += di;
            }
        }

        // ---- epilogue: layout [lvl1 | lvl2 | lvl3 | lvl4] ----
        float* ob = out + (size_t)b * OUT_PER_B;
        if (j == 0 && kq == 0) ob[i] = s1;                 // level 1
        if (kq == 0) ob[12 + i * 12 + j] = s2;             // level 2
        const int ijk = (i * 12 + j) * 12 + k0;
        #pragma unroll
        for (int q = 0; q < 4; ++q) ob[156 + ijk + q] = s3[q];   // level 3
        float4* o4 = (float4*)(ob + 1884 + (size_t)ijk * 12);    // level 4
        #pragma unroll
        for (int q = 0; q < 4; ++q) {
            o4[3 * q + 0] = make_float4(acc[q][0], acc[q][1], acc[q][2],  acc[q][3]);
            o4[3 * q + 1] = make_float4(acc[q][4], acc[q][5], acc[q][6],  acc[q][7]);
            o4[3 * q + 2] = make_float4(acc[q][8], acc[q][9], acc[q][10], acc[q][11]);
        }
    }
}

extern "C" void kernel_launch(void* const* d_in, const int* in_sizes, int n_in,
                              void* d_out, int out_size, void* d_ws, size_t ws_size,
                              hipStream_t stream) {
    const float* path = (const float*)d_in[0];
    float* out = (float*)d_out;
    const int nbatch = in_sizes[0] / (NPTS * NC);   // = 128
    sig_kernel<<<nbatch * 4, BLOCK, 0, stream>>>(path, out);
}